// Round 7
// baseline (587.052 us; speedup 1.0000x reference)
//
#include <hip/hip_runtime.h>
#include <stdint.h>

typedef unsigned int u32;
typedef unsigned short ushort_t;

#define T_ 4
#define B_ 16
#define C_ 256
#define N_ 1024
#define CN (C_ * N_)                 /* 262144 */
#define M_ELEMS (64 * C_ * N_)       /* 16777216 elems per [TB,C,N] tensor */

/* workspace byte offsets */
#define OFF_S    0ull                          /* SQ,SK,SV u8: 3*16.7MB */
#define OFF_XC   67108864ull                   /* Xc bf16 [64 tb][16 slab][1024 n][32 k] = 64MB; later aliased by Sc */
#define OFF_SC   67108864ull                   /* Sc bf16 [64 tb][8 kb][1024 n][32 k] = 32MB */
#define OFF_KV   134217728ull                  /* fp32 [64][8][32][32] = 2MB */
#define OFF_BNS  136314880ull                  /* 8KB */
#define OFF_WC   136323072ull                  /* Wc bf16 [3][256][768] = 1.125MB */
#define OFF_WPC  137502720ull                  /* Wpc bf16 [256][512] = 256KB */

typedef __attribute__((ext_vector_type(8))) short bf16x8;
typedef __attribute__((ext_vector_type(4))) float f32x4;

__device__ __forceinline__ ushort_t f2bf(float f) {
  u32 u = __float_as_uint(f);
  u32 r = (u + 0x7FFFu + ((u >> 16) & 1u)) >> 16;
  return (ushort_t)r;
}
__device__ __forceinline__ float bf2f(ushort_t h) { return __uint_as_float((u32)h << 16); }

/* ---- BN coefficient prep ---- */
__global__ void bn_prep(const float* __restrict__ qg, const float* __restrict__ qb2, const float* __restrict__ qm, const float* __restrict__ qv,
                        const float* __restrict__ kg, const float* __restrict__ kb, const float* __restrict__ km, const float* __restrict__ kvv,
                        const float* __restrict__ vg, const float* __restrict__ vb, const float* __restrict__ vm, const float* __restrict__ vv,
                        const float* __restrict__ pbias,
                        const float* __restrict__ pg, const float* __restrict__ pbt, const float* __restrict__ pm, const float* __restrict__ pv,
                        float* __restrict__ bns) {
  int i = threadIdx.x;  /* 1024 threads */
  int br = i >> 8, c = i & 255;
  const float *g, *bt, *m, *v;
  float bias = 0.f;
  if (br == 0)      { g = qg; bt = qb2; m = qm; v = qv; }
  else if (br == 1) { g = kg; bt = kb;  m = km; v = kvv; }
  else if (br == 2) { g = vg; bt = vb;  m = vm; v = vv; }
  else              { g = pg; bt = pbt; m = pm; v = pv; bias = pbias[c]; }
  float sc = g[c] / sqrtf(v[c] + 1e-5f);
  bns[2 * i] = sc;
  bns[2 * i + 1] = bt[c] + (bias - m[c]) * sc;
}

/* ---- split weights to bf16 hi/lo. Wc[br][256][768] = [hi|lo|unused]; Wpc[256][512] = [hi|lo] ---- */
__global__ __launch_bounds__(256) void convert_w(const float* __restrict__ qw, const float* __restrict__ kw,
                                                 const float* __restrict__ vw, const float* __restrict__ pw,
                                                 ushort_t* __restrict__ Wc, ushort_t* __restrict__ Wpc) {
  int id = blockIdx.x * 256 + threadIdx.x;   /* 4*65536 */
  int br = id >> 16, o = (id >> 8) & 255, c = id & 255;
  const float* w = (br == 0) ? qw : (br == 1) ? kw : (br == 2) ? vw : pw;
  float f = w[o * 256 + c];
  ushort_t hi = f2bf(f);
  ushort_t lo = f2bf(f - bf2f(hi));
  if (br < 3) {
    ushort_t* d = Wc + (size_t)br * 196608 + (size_t)o * 768 + c;
    d[0] = hi; d[256] = lo; d[512] = 0;
  } else {
    ushort_t* d = Wpc + (size_t)o * 512 + c;
    d[0] = hi; d[256] = lo;
  }
}

/* ---- x fp32 [tb][256 c][1024 n] -> Xc bf16 [tb][16 slab][1024 n][32 k]; slab kb<8 = hi, 8+kb = lo ---- */
__global__ __launch_bounds__(256) void convert_x(const float* __restrict__ x, ushort_t* __restrict__ Xc) {
  __shared__ ushort_t hi[32][260];
  __shared__ ushort_t lo[32][260];
  int bid = blockIdx.x;
  int nc = bid & 3, kb = (bid >> 2) & 7, tb = bid >> 5;
  int t = threadIdx.x;
  int n0 = nc * 256;
  const float* xb = x + (size_t)tb * CN + (size_t)(kb * 32) * N_ + n0;
#pragma unroll
  for (int p = 0; p < 8; ++p) {
    int k = p * 4 + (t >> 6);
    int n4 = (t & 63) * 4;
    float4 v = *(const float4*)&xb[(size_t)k * N_ + n4];
    ushort_t h0 = f2bf(v.x), h1 = f2bf(v.y), h2 = f2bf(v.z), h3 = f2bf(v.w);
    short4 hv = make_short4((short)h0, (short)h1, (short)h2, (short)h3);
    short4 lv = make_short4((short)f2bf(v.x - bf2f(h0)), (short)f2bf(v.y - bf2f(h1)),
                            (short)f2bf(v.z - bf2f(h2)), (short)f2bf(v.w - bf2f(h3)));
    *(short4*)&hi[k][n4] = hv;
    *(short4*)&lo[k][n4] = lv;
  }
  __syncthreads();
  ushort_t* Hs = Xc + ((size_t)(tb * 16 + kb) * 1024 + n0) * 32;
  ushort_t* Ls = Xc + ((size_t)(tb * 16 + 8 + kb) * 1024 + n0) * 32;
  int kq = t & 3;
#pragma unroll
  for (int q = 0; q < 4; ++q) {
    int n = q * 64 + (t >> 2);
    u32 a0 = (u32)hi[kq * 8 + 0][n] | ((u32)hi[kq * 8 + 1][n] << 16);
    u32 a1 = (u32)hi[kq * 8 + 2][n] | ((u32)hi[kq * 8 + 3][n] << 16);
    u32 a2 = (u32)hi[kq * 8 + 4][n] | ((u32)hi[kq * 8 + 5][n] << 16);
    u32 a3 = (u32)hi[kq * 8 + 6][n] | ((u32)hi[kq * 8 + 7][n] << 16);
    *(uint4*)(Hs + (size_t)n * 32 + kq * 8) = make_uint4(a0, a1, a2, a3);
    u32 b0 = (u32)lo[kq * 8 + 0][n] | ((u32)lo[kq * 8 + 1][n] << 16);
    u32 b1 = (u32)lo[kq * 8 + 2][n] | ((u32)lo[kq * 8 + 3][n] << 16);
    u32 b2 = (u32)lo[kq * 8 + 4][n] | ((u32)lo[kq * 8 + 5][n] << 16);
    u32 b3 = (u32)lo[kq * 8 + 6][n] | ((u32)lo[kq * 8 + 7][n] << 16);
    *(uint4*)(Ls + (size_t)n * 32 + kq * 8) = make_uint4(b0, b1, b2, b3);
  }
}

/* ---- fused q/k/v MFMA GEMM, flatmm-style: direct global->VGPR fragment loads,
   NO LDS staging / NO barriers in K-loop. Block 128m x 64n, 4 waves (32m x 64n each).
   grid 1536 1D: bid = b*96 + mt*16 + nt  (bid%8 == nt%8 -> mt-siblings share XCD). ---- */
__global__ __launch_bounds__(256, 3) void gemm_qkv_lif(
    const ushort_t* __restrict__ Wc, const ushort_t* __restrict__ Xc,
    const float* __restrict__ bns, uint8_t* __restrict__ S) {
  __shared__ uint8_t Stile[128 * 64];   /* 8KB epilogue spike tile */
  const int bid = blockIdx.x;
  const int nt = bid % 16, mt = (bid / 16) % 6, b = bid / 96;
  const int br = mt >> 1, rh = mt & 1;
  const ushort_t* Ab = Wc + (size_t)br * 196608 + (size_t)(rh * 128) * 768;
  const int tid = threadIdx.x;
  const int lane = tid & 63;
  const int quad = lane >> 4, r = lane & 15;
  const int w = tid >> 6;
  const int moff = w * 32;
  /* A fragment row pointers (f=0,1): lane reads 16B at k = s*32 + quad*8 (+256 for lo) */
  const ushort_t* A0p = Ab + (size_t)(moff + r) * 768 + quad * 8;
  const ushort_t* A1p = Ab + (size_t)(moff + 16 + r) * 768 + quad * 8;
  /* B fragment row pointers (g=0..3): contiguous 1KB per wave-load */
  const ushort_t* Brow[4];
#pragma unroll
  for (int g = 0; g < 4; ++g)
    Brow[g] = Xc + (size_t)(nt * 64 + g * 16 + r) * 32 + quad * 8;

  float mem[32];
#pragma unroll
  for (int i = 0; i < 32; ++i) mem[i] = 0.f;

  for (int t = 0; t < 4; ++t) {
    f32x4 acc[8];
#pragma unroll
    for (int i = 0; i < 8; ++i) acc[i] = (f32x4){0.f, 0.f, 0.f, 0.f};
    const size_t toff = (size_t)(t * 16 + b) * 524288;
    /* phase 1: X-hi slabs 0..7, dual-A (W-hi + W-lo): 16 MFMA / 8 loads per slab */
    for (int s = 0; s < 8; ++s) {
      const int ao = s * 32;
      const size_t bo = toff + (size_t)s * 32768;
      bf16x8 ah0 = *(const bf16x8*)(A0p + ao);
      bf16x8 ah1 = *(const bf16x8*)(A1p + ao);
      bf16x8 al0 = *(const bf16x8*)(A0p + 256 + ao);
      bf16x8 al1 = *(const bf16x8*)(A1p + 256 + ao);
      bf16x8 b0 = *(const bf16x8*)(Brow[0] + bo);
      bf16x8 b1 = *(const bf16x8*)(Brow[1] + bo);
      bf16x8 b2 = *(const bf16x8*)(Brow[2] + bo);
      bf16x8 b3 = *(const bf16x8*)(Brow[3] + bo);
      acc[0] = __builtin_amdgcn_mfma_f32_16x16x32_bf16(ah0, b0, acc[0], 0, 0, 0);
      acc[1] = __builtin_amdgcn_mfma_f32_16x16x32_bf16(ah0, b1, acc[1], 0, 0, 0);
      acc[2] = __builtin_amdgcn_mfma_f32_16x16x32_bf16(ah0, b2, acc[2], 0, 0, 0);
      acc[3] = __builtin_amdgcn_mfma_f32_16x16x32_bf16(ah0, b3, acc[3], 0, 0, 0);
      acc[4] = __builtin_amdgcn_mfma_f32_16x16x32_bf16(ah1, b0, acc[4], 0, 0, 0);
      acc[5] = __builtin_amdgcn_mfma_f32_16x16x32_bf16(ah1, b1, acc[5], 0, 0, 0);
      acc[6] = __builtin_amdgcn_mfma_f32_16x16x32_bf16(ah1, b2, acc[6], 0, 0, 0);
      acc[7] = __builtin_amdgcn_mfma_f32_16x16x32_bf16(ah1, b3, acc[7], 0, 0, 0);
      acc[0] = __builtin_amdgcn_mfma_f32_16x16x32_bf16(al0, b0, acc[0], 0, 0, 0);
      acc[1] = __builtin_amdgcn_mfma_f32_16x16x32_bf16(al0, b1, acc[1], 0, 0, 0);
      acc[2] = __builtin_amdgcn_mfma_f32_16x16x32_bf16(al0, b2, acc[2], 0, 0, 0);
      acc[3] = __builtin_amdgcn_mfma_f32_16x16x32_bf16(al0, b3, acc[3], 0, 0, 0);
      acc[4] = __builtin_amdgcn_mfma_f32_16x16x32_bf16(al1, b0, acc[4], 0, 0, 0);
      acc[5] = __builtin_amdgcn_mfma_f32_16x16x32_bf16(al1, b1, acc[5], 0, 0, 0);
      acc[6] = __builtin_amdgcn_mfma_f32_16x16x32_bf16(al1, b2, acc[6], 0, 0, 0);
      acc[7] = __builtin_amdgcn_mfma_f32_16x16x32_bf16(al1, b3, acc[7], 0, 0, 0);
    }
    /* phase 2: X-lo slabs 8..15 vs W-hi (same k block s-8): 8 MFMA / 6 loads per slab */
    for (int s = 8; s < 16; ++s) {
      const int ao = (s - 8) * 32;
      const size_t bo = toff + (size_t)s * 32768;
      bf16x8 ah0 = *(const bf16x8*)(A0p + ao);
      bf16x8 ah1 = *(const bf16x8*)(A1p + ao);
      bf16x8 b0 = *(const bf16x8*)(Brow[0] + bo);
      bf16x8 b1 = *(const bf16x8*)(Brow[1] + bo);
      bf16x8 b2 = *(const bf16x8*)(Brow[2] + bo);
      bf16x8 b3 = *(const bf16x8*)(Brow[3] + bo);
      acc[0] = __builtin_amdgcn_mfma_f32_16x16x32_bf16(ah0, b0, acc[0], 0, 0, 0);
      acc[1] = __builtin_amdgcn_mfma_f32_16x16x32_bf16(ah0, b1, acc[1], 0, 0, 0);
      acc[2] = __builtin_amdgcn_mfma_f32_16x16x32_bf16(ah0, b2, acc[2], 0, 0, 0);
      acc[3] = __builtin_amdgcn_mfma_f32_16x16x32_bf16(ah0, b3, acc[3], 0, 0, 0);
      acc[4] = __builtin_amdgcn_mfma_f32_16x16x32_bf16(ah1, b0, acc[4], 0, 0, 0);
      acc[5] = __builtin_amdgcn_mfma_f32_16x16x32_bf16(ah1, b1, acc[5], 0, 0, 0);
      acc[6] = __builtin_amdgcn_mfma_f32_16x16x32_bf16(ah1, b2, acc[6], 0, 0, 0);
      acc[7] = __builtin_amdgcn_mfma_f32_16x16x32_bf16(ah1, b3, acc[7], 0, 0, 0);
    }
    /* epilogue: BN + LIF into LDS spike tile, then coalesced u8 stores */
#pragma unroll
    for (int f = 0; f < 2; ++f) {
#pragma unroll
      for (int rg = 0; rg < 4; ++rg) {
        int cl = moff + f * 16 + quad * 4 + rg;
        int c = rh * 128 + cl;
        float sc = bns[2 * (br * 256 + c)];
        float sh = bns[2 * (br * 256 + c) + 1];
#pragma unroll
        for (int g = 0; g < 4; ++g) {
          float y = acc[f * 4 + g][rg] * sc + sh;
          float m = mem[(f * 4 + g) * 4 + rg];
          m += (y - m) * 0.5f;
          uint8_t sp = (m >= 1.0f) ? 1 : 0;
          Stile[cl * 64 + g * 16 + r] = sp;
          mem[(f * 4 + g) * 4 + rg] = sp ? 0.f : m;
        }
      }
    }
    __syncthreads();
    {
      uint8_t* Sb = S + (size_t)br * M_ELEMS + (size_t)(t * 16 + b) * CN;
      const int row = tid >> 1, half = tid & 1;
      uint8_t* gdst = Sb + (size_t)(rh * 128 + row) * N_ + nt * 64 + half * 32;
      const uint8_t* lsrc = Stile + row * 64 + half * 32;
      *(uint4*)(gdst) = *(const uint4*)(lsrc);
      *(uint4*)(gdst + 16) = *(const uint4*)(lsrc + 16);
    }
    __syncthreads();
  }
}

/* ---- v spikes [T,B,C,N] u8 -> d_out v fp32 [T,B,H,N,D] ---- */
__global__ __launch_bounds__(256) void transpose_v(const uint8_t* __restrict__ SV, float* __restrict__ vout) {
  size_t o4 = ((size_t)blockIdx.x * 256 + threadIdx.x) * 4;
  int dd = (int)(o4 & 31);
  int n = (int)((o4 >> 5) & 1023);
  int h = (int)((o4 >> 15) & 7);
  int tb = (int)(o4 >> 18);
  const uint8_t* src = SV + (size_t)tb * CN + (size_t)(h * 32 + dd) * N_ + n;
  *(float4*)(vout + o4) = make_float4((float)src[0], (float)src[(size_t)N_],
                                      (float)src[2 * (size_t)N_], (float)src[3 * (size_t)N_]);
}

/* ---- kv gram via MFMA: block per (tb,h), 4 waves split N, LDS reduce ---- */
__device__ __forceinline__ bf16x8 unpack_spk(uint2 u) {
  bf16x8 o;
  o[0] = (short)((u.x & 1u) ? 0x3F80 : 0);
  o[1] = (short)(((u.x >> 8) & 1u) ? 0x3F80 : 0);
  o[2] = (short)(((u.x >> 16) & 1u) ? 0x3F80 : 0);
  o[3] = (short)(((u.x >> 24) & 1u) ? 0x3F80 : 0);
  o[4] = (short)((u.y & 1u) ? 0x3F80 : 0);
  o[5] = (short)(((u.y >> 8) & 1u) ? 0x3F80 : 0);
  o[6] = (short)(((u.y >> 16) & 1u) ? 0x3F80 : 0);
  o[7] = (short)(((u.y >> 24) & 1u) ? 0x3F80 : 0);
  return o;
}

__global__ __launch_bounds__(256) void kv_gram(const uint8_t* __restrict__ SK,
                                               const uint8_t* __restrict__ SV,
                                               float* __restrict__ KV) {
  __shared__ float red[4096];
  const int tb = blockIdx.x >> 3, h = blockIdx.x & 7;
  const uint8_t* K = SK + (size_t)tb * CN + (size_t)h * 32 * N_;
  const uint8_t* V = SV + (size_t)tb * CN + (size_t)h * 32 * N_;
  const int tid = threadIdx.x;
  const int w = tid >> 6, lane = tid & 63;
  const int quad = lane >> 4, r = lane & 15;
  f32x4 acc[4];
#pragma unroll
  for (int f = 0; f < 4; ++f) acc[f] = (f32x4){0.f, 0.f, 0.f, 0.f};
#pragma unroll
  for (int ks = 0; ks < 8; ++ks) {
    int n0 = w * 256 + ks * 32 + quad * 8;
    bf16x8 ka = unpack_spk(*(const uint2*)(K + (size_t)r * N_ + n0));
    bf16x8 kb = unpack_spk(*(const uint2*)(K + (size_t)(16 + r) * N_ + n0));
    bf16x8 va = unpack_spk(*(const uint2*)(V + (size_t)r * N_ + n0));
    bf16x8 vb = unpack_spk(*(const uint2*)(V + (size_t)(16 + r) * N_ + n0));
    acc[0] = __builtin_amdgcn_mfma_f32_16x16x32_bf16(ka, va, acc[0], 0, 0, 0);
    acc[1] = __builtin_amdgcn_mfma_f32_16x16x32_bf16(ka, vb, acc[1], 0, 0, 0);
    acc[2] = __builtin_amdgcn_mfma_f32_16x16x32_bf16(kb, va, acc[2], 0, 0, 0);
    acc[3] = __builtin_amdgcn_mfma_f32_16x16x32_bf16(kb, vb, acc[3], 0, 0, 0);
  }
#pragma unroll
  for (int f = 0; f < 4; ++f) {
    int d0 = (f >> 1) * 16 + quad * 4;
    int e = (f & 1) * 16 + r;
#pragma unroll
    for (int rg = 0; rg < 4; ++rg) red[w * 1024 + (d0 + rg) * 32 + e] = acc[f][rg];
  }
  __syncthreads();
  int idx = tid * 4;
  float4 s0 = *(const float4*)&red[idx];
  float4 s1 = *(const float4*)&red[1024 + idx];
  float4 s2 = *(const float4*)&red[2048 + idx];
  float4 s3 = *(const float4*)&red[3072 + idx];
  float4 o = make_float4(s0.x + s1.x + s2.x + s3.x, s0.y + s1.y + s2.y + s3.y,
                         s0.z + s1.z + s2.z + s3.z, s0.w + s1.w + s2.w + s3.w);
  *(float4*)&KV[(size_t)(tb * 8 + h) * 1024 + idx] = o;
}

/* ---- fused attn + LIF(0.5) -> bf16 spikes Sc [tb][8 kb][1024 n][32 k] ---- */
__global__ __launch_bounds__(256) void attn_lif(const uint8_t* __restrict__ SQ,
                                                const float* __restrict__ KV,
                                                ushort_t* __restrict__ Sc) {
  __shared__ float kvs[1024];
  const int bid = blockIdx.x;
  const int nb = bid & 15, h = (bid >> 4) & 7, b = bid >> 7;
  const int n0 = nb * 64;
  const int tid = threadIdx.x;
  const int nl = tid & 63, eg = tid >> 6;
  float mem[8];
#pragma unroll
  for (int j = 0; j < 8; ++j) mem[j] = 0.f;
  for (int t = 0; t < 4; ++t) {
    const float* kvp = KV + (size_t)((t * B_ + b) * 8 + h) * 1024;
    *(float4*)&kvs[tid * 4] = *(const float4*)&kvp[tid * 4];
    __syncthreads();
    const uint8_t* q = SQ + (size_t)(t * B_ + b) * CN + (size_t)h * 32 * N_ + n0 + nl;
    float val[8];
#pragma unroll
    for (int j = 0; j < 8; ++j) val[j] = 0.f;
#pragma unroll 4
    for (int dd = 0; dd < 32; ++dd) {
      float qv = (float)q[(size_t)dd * N_];
#pragma unroll
      for (int j = 0; j < 8; ++j) val[j] += qv * kvs[dd * 32 + eg * 8 + j];
    }
    ushort_t pk[8];
#pragma unroll
    for (int j = 0; j < 8; ++j) {
      float a = val[j] * 0.125f;
      mem[j] += (a - mem[j]) * 0.5f;
      int s = (mem[j] >= 0.5f);
      pk[j] = s ? (ushort_t)0x3F80 : (ushort_t)0;
      if (s) mem[j] = 0.f;
    }
    uint4 o;
    o.x = (u32)pk[0] | ((u32)pk[1] << 16);
    o.y = (u32)pk[2] | ((u32)pk[3] << 16);
    o.z = (u32)pk[4] | ((u32)pk[5] << 16);
    o.w = (u32)pk[6] | ((u32)pk[7] << 16);
    *(uint4*)(Sc + ((size_t)((t * B_ + b) * 8 + h) * 1024 + n0 + nl) * 32 + eg * 8) = o;
    __syncthreads();
  }
}

/* ---- p projection, flatmm-style direct loads + BN + final LIF -> fp32 spikes.
   Block 128m x 64n, 4 waves; grid 512 1D: bid = b*32 + mt*16 + nt. ---- */
__global__ __launch_bounds__(256, 3) void gemm_p_lif(
    const ushort_t* __restrict__ Wpc, const ushort_t* __restrict__ Sc,
    const float* __restrict__ bns, float* __restrict__ out) {
  const int bid = blockIdx.x;
  const int nt = bid % 16, mt = (bid / 16) & 1, b = bid / 32;
  const ushort_t* Ab = Wpc + (size_t)(mt * 128) * 512;
  const int tid = threadIdx.x;
  const int lane = tid & 63;
  const int quad = lane >> 4, r = lane & 15;
  const int w = tid >> 6;
  const int moff = w * 32;
  const ushort_t* A0p = Ab + (size_t)(moff + r) * 512 + quad * 8;
  const ushort_t* A1p = Ab + (size_t)(moff + 16 + r) * 512 + quad * 8;
  const ushort_t* Brow[4];
#pragma unroll
  for (int g = 0; g < 4; ++g)
    Brow[g] = Sc + (size_t)(nt * 64 + g * 16 + r) * 32 + quad * 8;

  float mem[32];
#pragma unroll
  for (int i = 0; i < 32; ++i) mem[i] = 0.f;

  for (int t = 0; t < 4; ++t) {
    f32x4 acc[8];
#pragma unroll
    for (int i = 0; i < 8; ++i) acc[i] = (f32x4){0.f, 0.f, 0.f, 0.f};
    const size_t toff = (size_t)(t * 16 + b) * 262144;
    for (int s = 0; s < 8; ++s) {
      const int ao = s * 32;
      const size_t bo = toff + (size_t)s * 32768;
      bf16x8 ah0 = *(const bf16x8*)(A0p + ao);
      bf16x8 ah1 = *(const bf16x8*)(A1p + ao);
      bf16x8 al0 = *(const bf16x8*)(A0p + 256 + ao);
      bf16x8 al1 = *(const bf16x8*)(A1p + 256 + ao);
      bf16x8 b0 = *(const bf16x8*)(Brow[0] + bo);
      bf16x8 b1 = *(const bf16x8*)(Brow[1] + bo);
      bf16x8 b2 = *(const bf16x8*)(Brow[2] + bo);
      bf16x8 b3 = *(const bf16x8*)(Brow[3] + bo);
      acc[0] = __builtin_amdgcn_mfma_f32_16x16x32_bf16(ah0, b0, acc[0], 0, 0, 0);
      acc[1] = __builtin_amdgcn_mfma_f32_16x16x32_bf16(ah0, b1, acc[1], 0, 0, 0);
      acc[2] = __builtin_amdgcn_mfma_f32_16x16x32_bf16(ah0, b2, acc[2], 0, 0, 0);
      acc[3] = __builtin_amdgcn_mfma_f32_16x16x32_bf16(ah0, b3, acc[3], 0, 0, 0);
      acc[4] = __builtin_amdgcn_mfma_f32_16x16x32_bf16(ah1, b0, acc[4], 0, 0, 0);
      acc[5] = __builtin_amdgcn_mfma_f32_16x16x32_bf16(ah1, b1, acc[5], 0, 0, 0);
      acc[6] = __builtin_amdgcn_mfma_f32_16x16x32_bf16(ah1, b2, acc[6], 0, 0, 0);
      acc[7] = __builtin_amdgcn_mfma_f32_16x16x32_bf16(ah1, b3, acc[7], 0, 0, 0);
      acc[0] = __builtin_amdgcn_mfma_f32_16x16x32_bf16(al0, b0, acc[0], 0, 0, 0);
      acc[1] = __builtin_amdgcn_mfma_f32_16x16x32_bf16(al0, b1, acc[1], 0, 0, 0);
      acc[2] = __builtin_amdgcn_mfma_f32_16x16x32_bf16(al0, b2, acc[2], 0, 0, 0);
      acc[3] = __builtin_amdgcn_mfma_f32_16x16x32_bf16(al0, b3, acc[3], 0, 0, 0);
      acc[4] = __builtin_amdgcn_mfma_f32_16x16x32_bf16(al1, b0, acc[4], 0, 0, 0);
      acc[5] = __builtin_amdgcn_mfma_f32_16x16x32_bf16(al1, b1, acc[5], 0, 0, 0);
      acc[6] = __builtin_amdgcn_mfma_f32_16x16x32_bf16(al1, b2, acc[6], 0, 0, 0);
      acc[7] = __builtin_amdgcn_mfma_f32_16x16x32_bf16(al1, b3, acc[7], 0, 0, 0);
    }
    /* epilogue: BN + final LIF(1.0) -> fp32 spikes */
    float* Ob = out + (size_t)(t * 16 + b) * CN;
#pragma unroll
    for (int f = 0; f < 2; ++f) {
#pragma unroll
      for (int rg = 0; rg < 4; ++rg) {
        int c = mt * 128 + moff + f * 16 + quad * 4 + rg;
        float sc = bns[2 * (768 + c)];
        float sh = bns[2 * (768 + c) + 1];
#pragma unroll
        for (int g = 0; g < 4; ++g) {
          float y = acc[f * 4 + g][rg] * sc + sh;
          float m = mem[(f * 4 + g) * 4 + rg];
          m += (y - m) * 0.5f;
          float sp = (m >= 1.0f) ? 1.f : 0.f;
          Ob[(size_t)c * N_ + nt * 64 + g * 16 + r] = sp;
          mem[(f * 4 + g) * 4 + rg] = m * (1.f - sp);
        }
      }
    }
  }
}

extern "C" void kernel_launch(void* const* d_in, const int* in_sizes, int n_in,
                              void* d_out, int out_size, void* d_ws, size_t ws_size,
                              hipStream_t stream) {
  const float* x   = (const float*)d_in[0];
  const float* qw  = (const float*)d_in[2];
  const float* qg  = (const float*)d_in[3];
  const float* qb  = (const float*)d_in[4];
  const float* qm  = (const float*)d_in[5];
  const float* qv  = (const float*)d_in[6];
  const float* kw  = (const float*)d_in[7];
  const float* kg  = (const float*)d_in[8];
  const float* kb  = (const float*)d_in[9];
  const float* km  = (const float*)d_in[10];
  const float* kvv = (const float*)d_in[11];
  const float* vw  = (const float*)d_in[12];
  const float* vg  = (const float*)d_in[13];
  const float* vb  = (const float*)d_in[14];
  const float* vm  = (const float*)d_in[15];
  const float* vv  = (const float*)d_in[16];
  const float* pw  = (const float*)d_in[17];
  const float* pb  = (const float*)d_in[18];
  const float* pg  = (const float*)d_in[19];
  const float* pbt = (const float*)d_in[20];
  const float* pm  = (const float*)d_in[21];
  const float* pv  = (const float*)d_in[22];

  float* out = (float*)d_out;
  float* vout = out + M_ELEMS;

  uint8_t* ws = (uint8_t*)d_ws;
  uint8_t* S   = ws + OFF_S;          /* SQ | SK | SV */
  ushort_t* Xc = (ushort_t*)(ws + OFF_XC);
  ushort_t* Sc = (ushort_t*)(ws + OFF_SC);
  float* KV    = (float*)(ws + OFF_KV);
  float* BNS   = (float*)(ws + OFF_BNS);
  ushort_t* Wcw = (ushort_t*)(ws + OFF_WC);
  ushort_t* Wpc = (ushort_t*)(ws + OFF_WPC);

  bn_prep<<<dim3(1), dim3(1024), 0, stream>>>(qg, qb, qm, qv, kg, kb, km, kvv,
                                              vg, vb, vm, vv, pb, pg, pbt, pm, pv, BNS);
  convert_w<<<dim3(1024), dim3(256), 0, stream>>>(qw, kw, vw, pw, Wcw, Wpc);
  convert_x<<<dim3(2048), dim3(256), 0, stream>>>(x, Xc);
  gemm_qkv_lif<<<dim3(1536), dim3(256), 0, stream>>>(Wcw, Xc, BNS, S);
  transpose_v<<<dim3(16384), dim3(256), 0, stream>>>(S + 2ull * M_ELEMS, vout);
  kv_gram<<<dim3(512), dim3(256), 0, stream>>>(S + 1ull * M_ELEMS, S + 2ull * M_ELEMS, KV);
  attn_lif<<<dim3(2048), dim3(256), 0, stream>>>(S, KV, Sc);
  gemm_p_lif<<<dim3(512), dim3(256), 0, stream>>>(Wpc, Sc, BNS, out);
}